// Round 6
// baseline (92.343 us; speedup 1.0000x reference)
//
#include <hip/hip_runtime.h>
#include <math.h>

#define Bv 2
#define Dv 192
#define Hv 192
#define Wv 192
#define Nv (Dv*Hv*Wv)          // 7,077,888 voxels per batch
#define NOUT (Bv*Nv)           // 14,155,776 warped elements

// Block tile: 8x8x8 = 512 threads. Each wave is a 4x4x4 output cube --
// minimizes the wave's source-space footprint (distinct cache lines per
// gather) under a generic rotation+shear, which is the measured limiter.

__device__ __forceinline__ void mm3(const float a[3][3], const float b[3][3], float c[3][3]) {
#pragma unroll
    for (int i = 0; i < 3; ++i)
#pragma unroll
        for (int j = 0; j < 3; ++j)
            c[i][j] = a[i][0]*b[0][j] + a[i][1]*b[1][j] + a[i][2]*b[2][j];
}

__global__ void compose_mats_kernel(const float* __restrict__ affine,
                                    const float* __restrict__ scale,
                                    const float* __restrict__ translate,
                                    const float* __restrict__ shear,
                                    float* __restrict__ mats_out) {
    int b = threadIdx.x;
    if (b >= Bv) return;

    float ax = affine[b*3+0], ay = affine[b*3+1], az = affine[b*3+2];
    float cx = cosf(ax), sx = sinf(ax);
    float cy = cosf(ay), sy = sinf(ay);
    float cz = cosf(az), sz = sinf(az);

    // _mk_mat transposes the written rows -> these are the transposed matrices.
    float rx[3][3] = {{1.f,0.f,0.f},{0.f,cx,sx},{0.f,-sx,cx}};
    float ry[3][3] = {{cy,0.f,-sy},{0.f,1.f,0.f},{sy,0.f,cy}};
    float rz[3][3] = {{cz,sz,0.f},{-sz,cz,0.f},{0.f,0.f,1.f}};

    float t0 = tanf(shear[b*6+0]), t1 = tanf(shear[b*6+1]), t2 = tanf(shear[b*6+2]);
    float t3 = tanf(shear[b*6+3]), t4 = tanf(shear[b*6+4]), t5 = tanf(shear[b*6+5]);
    float sh[3][3] = {{1.f,t2,t4},{t0,1.f,t5},{t1,t3,1.f}};

    float s0 = scale[b*3+0], s1 = scale[b*3+1], s2 = scale[b*3+2];

    float m1[3][3], m2[3][3], m3s[3][3], mat3[3][3];
    mm3(ry, rx, m1);
    mm3(rz, m1, m2);
#pragma unroll
    for (int j = 0; j < 3; ++j) { m3s[0][j] = s0*m2[0][j]; m3s[1][j] = s1*m2[1][j]; m3s[2][j] = s2*m2[2][j]; }
    mm3(sh, m3s, mat3);

    float tr0 = translate[b*3+0], tr1 = translate[b*3+1], tr2 = translate[b*3+2];

    float a00 = mat3[0][0], a01 = mat3[0][1], a02 = mat3[0][2];
    float a10 = mat3[1][0], a11 = mat3[1][1], a12 = mat3[1][2];
    float a20 = mat3[2][0], a21 = mat3[2][1], a22 = mat3[2][2];
    float c00 =  (a11*a22 - a12*a21);
    float c01 = -(a10*a22 - a12*a20);
    float c02 =  (a10*a21 - a11*a20);
    float det = a00*c00 + a01*c01 + a02*c02;
    float rdet = 1.0f / det;
    float inv3[3][3];
    inv3[0][0] = c00*rdet;
    inv3[0][1] = (a02*a21 - a01*a22)*rdet;
    inv3[0][2] = (a01*a12 - a02*a11)*rdet;
    inv3[1][0] = c01*rdet;
    inv3[1][1] = (a00*a22 - a02*a20)*rdet;
    inv3[1][2] = (a02*a10 - a00*a12)*rdet;
    inv3[2][0] = c02*rdet;
    inv3[2][1] = (a01*a20 - a00*a21)*rdet;
    inv3[2][2] = (a00*a11 - a01*a10)*rdet;

    float* mo = mats_out + b*12;
#pragma unroll
    for (int i = 0; i < 3; ++i) {
        mo[i*4+0] = mat3[i][0]; mo[i*4+1] = mat3[i][1]; mo[i*4+2] = mat3[i][2];
    }
    mo[0*4+3] = tr0; mo[1*4+3] = tr1; mo[2*4+3] = tr2;

    float* io = mats_out + 24 + b*12;
#pragma unroll
    for (int i = 0; i < 3; ++i) {
        io[i*4+0] = inv3[i][0]; io[i*4+1] = inv3[i][1]; io[i*4+2] = inv3[i][2];
        io[i*4+3] = -(inv3[i][0]*tr0 + inv3[i][1]*tr1 + inv3[i][2]*tr2);
    }
}

// 8-byte load from a 4-byte-aligned address (single global_load_dwordx2).
__device__ __forceinline__ float2 ld2(const float* p) {
    float2 r;
    __builtin_memcpy(&r, p, 8);
    return r;
}

__global__ __launch_bounds__(512) void warp_kernel(const float* __restrict__ src,
                                                   const float* __restrict__ mats,
                                                   float* __restrict__ out) {
    int t    = threadIdx.x;
    int lane = t & 63;
    int wv   = t >> 6;              // 0..7

    // wave = 4x4x4 output cube; block = 2x2x2 waves = 8x8x8 tile
    int lx = (lane & 3)        + ((wv & 1) << 2);
    int ly = ((lane >> 2) & 3) + (((wv >> 1) & 1) << 2);
    int lz = (lane >> 4)       + (((wv >> 2) & 1) << 2);

    int w = blockIdx.x * 8 + lx;
    int h = blockIdx.y * 8 + ly;
    int zt = blockIdx.z;            // 0 .. (Dv/8)*Bv - 1
    int b  = zt / (Dv/8);           // uniform
    int z  = (zt % (Dv/8)) * 8 + lz;

    const float* M = mats + b*12;   // uniform -> scalar loads
    float m00 = M[0], m01 = M[1],  m02 = M[2],  m03 = M[3];
    float m10 = M[4], m11 = M[5],  m12 = M[6],  m13 = M[7];
    float m20 = M[8], m21 = M[9],  m22 = M[10], m23 = M[11];

    // ix = m00*(w+.5) + m01*(h+.5) + m02*(z+.5) + Cx
    float Cx = 96.0f*(m03 - m00 - m01 - m02) + 95.5f;
    float Cy = 96.0f*(m13 - m10 - m11 - m12) + 95.5f;
    float Cz = 96.0f*(m23 - m20 - m21 - m22) + 95.5f;

    float fw = w + 0.5f, fh = h + 0.5f, fzc = z + 0.5f;
    float ix = fmaf(m00, fw, fmaf(m01, fh, fmaf(m02, fzc, Cx)));
    float iy = fmaf(m10, fw, fmaf(m11, fh, fmaf(m12, fzc, Cy)));
    float iz = fmaf(m20, fw, fmaf(m21, fh, fmaf(m22, fzc, Cz)));

    float flx = floorf(ix), fly = floorf(iy), flz = floorf(iz);
    float wx = ix - flx, wy = iy - fly, wz = iz - flz;
    int x0 = (int)flx, y0 = (int)fly, z0 = (int)flz;

    const float* sb = src + (size_t)b * Nv;

    float acc = 0.0f;

    // interior: x0 in [0,190] etc  <=>  (unsigned)x0 < 191
    bool all_in = ((unsigned)x0 < (unsigned)(Wv-1)) &
                  ((unsigned)y0 < (unsigned)(Hv-1)) &
                  ((unsigned)z0 < (unsigned)(Dv-1));

    if (all_in) {
        const float* p = sb + ((z0*Hv + y0)*Wv + x0);
        const float* q = p + Hv*Wv;
        float2 v00 = ld2(p);
        float2 v01 = ld2(p + Wv);
        float2 v10 = ld2(q);
        float2 v11 = ld2(q + Wv);
        float c00 = fmaf(wx, v00.y - v00.x, v00.x);
        float c01 = fmaf(wx, v01.y - v01.x, v01.x);
        float c10 = fmaf(wx, v10.y - v10.x, v10.x);
        float c11 = fmaf(wx, v11.y - v11.x, v11.x);
        float c0  = fmaf(wy, c01 - c00, c00);
        float c1  = fmaf(wy, c11 - c10, c10);
        acc = fmaf(wz, c1 - c0, c0);
    } else {
        int x1 = x0 + 1, y1 = y0 + 1, z1 = z0 + 1;
        bool all_out = (x1 < 0) | (x0 >= Wv) | (y1 < 0) | (y0 >= Hv) | (z1 < 0) | (z0 >= Dv);
        if (!all_out) {
            auto gather = [&](int zz, int yy, int xx) -> float {
                bool valid = ((unsigned)xx < (unsigned)Wv) &
                             ((unsigned)yy < (unsigned)Hv) &
                             ((unsigned)zz < (unsigned)Dv);
                int xi = min(max(xx, 0), Wv-1);
                int yi = min(max(yy, 0), Hv-1);
                int zi = min(max(zz, 0), Dv-1);
                float val = sb[(zi*Hv + yi)*Wv + xi];
                return valid ? val : 0.0f;
            };
            float owx = 1.0f - wx, owy = 1.0f - wy, owz = 1.0f - wz;
            acc  = gather(z0, y0, x0) * (owz*owy*owx);
            acc += gather(z0, y0, x1) * (owz*owy*wx);
            acc += gather(z0, y1, x0) * (owz*wy*owx);
            acc += gather(z0, y1, x1) * (owz*wy*wx);
            acc += gather(z1, y0, x0) * (wz*owy*owx);
            acc += gather(z1, y0, x1) * (wz*owy*wx);
            acc += gather(z1, y1, x0) * (wz*wy*owx);
            acc += gather(z1, y1, x1) * (wz*wy*wx);
        }
    }

    __builtin_nontemporal_store(acc, &out[((size_t)(b*Dv + z)*Hv + h)*Wv + w]);
}

extern "C" void kernel_launch(void* const* d_in, const int* in_sizes, int n_in,
                              void* d_out, int out_size, void* d_ws, size_t ws_size,
                              hipStream_t stream) {
    const float* src       = (const float*)d_in[0];
    const float* affine    = (const float*)d_in[1];
    const float* scale     = (const float*)d_in[2];
    const float* translate = (const float*)d_in[3];
    const float* shear     = (const float*)d_in[4];

    float* out  = (float*)d_out;
    float* mats = out + NOUT;   // mat (24 floats) then inv_mat (24 floats)

    compose_mats_kernel<<<1, 64, 0, stream>>>(affine, scale, translate, shear, mats);

    dim3 grid(Wv/8, Hv/8, (Dv/8)*Bv);
    warp_kernel<<<grid, 512, 0, stream>>>(src, mats, out);
}

// Round 7
// 60.503 us; speedup vs baseline: 1.5263x; 1.5263x over previous
//
#include <hip/hip_runtime.h>
#include <math.h>

#define Bv 2
#define Dv 192
#define Hv 192
#define Wv 192
#define Nv (Dv*Hv*Wv)          // 7,077,888 voxels per batch
#define NOUT (Bv*Nv)           // 14,155,776 warped elements

// Block tile: 16(x) x 8(y) x 4(z) = 512 threads.
// GATHER mapping: waves = 4x4x4 cubes (4x2x1 waves) -> minimal source-line
//   footprint per wave vmem op (R6: FETCH 17.2->13.9 MB).
// STORE mapping: linear tid -> each wave stores 4 full 64B lines (R6 fix:
//   cube-shaped stores cost +54% WRITE_SIZE). Decoupled via 2KB LDS transpose.

__device__ __forceinline__ void mm3(const float a[3][3], const float b[3][3], float c[3][3]) {
#pragma unroll
    for (int i = 0; i < 3; ++i)
#pragma unroll
        for (int j = 0; j < 3; ++j)
            c[i][j] = a[i][0]*b[0][j] + a[i][1]*b[1][j] + a[i][2]*b[2][j];
}

__global__ void compose_mats_kernel(const float* __restrict__ affine,
                                    const float* __restrict__ scale,
                                    const float* __restrict__ translate,
                                    const float* __restrict__ shear,
                                    float* __restrict__ mats_out) {
    int b = threadIdx.x;
    if (b >= Bv) return;

    float ax = affine[b*3+0], ay = affine[b*3+1], az = affine[b*3+2];
    float cx = cosf(ax), sx = sinf(ax);
    float cy = cosf(ay), sy = sinf(ay);
    float cz = cosf(az), sz = sinf(az);

    // _mk_mat transposes the written rows -> these are the transposed matrices.
    float rx[3][3] = {{1.f,0.f,0.f},{0.f,cx,sx},{0.f,-sx,cx}};
    float ry[3][3] = {{cy,0.f,-sy},{0.f,1.f,0.f},{sy,0.f,cy}};
    float rz[3][3] = {{cz,sz,0.f},{-sz,cz,0.f},{0.f,0.f,1.f}};

    float t0 = tanf(shear[b*6+0]), t1 = tanf(shear[b*6+1]), t2 = tanf(shear[b*6+2]);
    float t3 = tanf(shear[b*6+3]), t4 = tanf(shear[b*6+4]), t5 = tanf(shear[b*6+5]);
    float sh[3][3] = {{1.f,t2,t4},{t0,1.f,t5},{t1,t3,1.f}};

    float s0 = scale[b*3+0], s1 = scale[b*3+1], s2 = scale[b*3+2];

    float m1[3][3], m2[3][3], m3s[3][3], mat3[3][3];
    mm3(ry, rx, m1);
    mm3(rz, m1, m2);
#pragma unroll
    for (int j = 0; j < 3; ++j) { m3s[0][j] = s0*m2[0][j]; m3s[1][j] = s1*m2[1][j]; m3s[2][j] = s2*m2[2][j]; }
    mm3(sh, m3s, mat3);

    float tr0 = translate[b*3+0], tr1 = translate[b*3+1], tr2 = translate[b*3+2];

    float a00 = mat3[0][0], a01 = mat3[0][1], a02 = mat3[0][2];
    float a10 = mat3[1][0], a11 = mat3[1][1], a12 = mat3[1][2];
    float a20 = mat3[2][0], a21 = mat3[2][1], a22 = mat3[2][2];
    float c00 =  (a11*a22 - a12*a21);
    float c01 = -(a10*a22 - a12*a20);
    float c02 =  (a10*a21 - a11*a20);
    float det = a00*c00 + a01*c01 + a02*c02;
    float rdet = 1.0f / det;
    float inv3[3][3];
    inv3[0][0] = c00*rdet;
    inv3[0][1] = (a02*a21 - a01*a22)*rdet;
    inv3[0][2] = (a01*a12 - a02*a11)*rdet;
    inv3[1][0] = c01*rdet;
    inv3[1][1] = (a00*a22 - a02*a20)*rdet;
    inv3[1][2] = (a02*a10 - a00*a12)*rdet;
    inv3[2][0] = c02*rdet;
    inv3[2][1] = (a01*a20 - a00*a21)*rdet;
    inv3[2][2] = (a00*a11 - a01*a10)*rdet;

    float* mo = mats_out + b*12;
#pragma unroll
    for (int i = 0; i < 3; ++i) {
        mo[i*4+0] = mat3[i][0]; mo[i*4+1] = mat3[i][1]; mo[i*4+2] = mat3[i][2];
    }
    mo[0*4+3] = tr0; mo[1*4+3] = tr1; mo[2*4+3] = tr2;

    float* io = mats_out + 24 + b*12;
#pragma unroll
    for (int i = 0; i < 3; ++i) {
        io[i*4+0] = inv3[i][0]; io[i*4+1] = inv3[i][1]; io[i*4+2] = inv3[i][2];
        io[i*4+3] = -(inv3[i][0]*tr0 + inv3[i][1]*tr1 + inv3[i][2]*tr2);
    }
}

// 8-byte load from a 4-byte-aligned address (single global_load_dwordx2).
__device__ __forceinline__ float2 ld2(const float* p) {
    float2 r;
    __builtin_memcpy(&r, p, 8);
    return r;
}

__global__ __launch_bounds__(512) void warp_kernel(const float* __restrict__ src,
                                                   const float* __restrict__ mats,
                                                   float* __restrict__ out) {
    __shared__ float tileO[512];

    int t    = threadIdx.x;
    int lane = t & 63;
    int wv   = t >> 6;              // 0..7
    int wvx  = wv & 3;              // waves tile 4x2x1
    int wvy  = wv >> 2;

    // gather mapping: wave = 4x4x4 cube
    int lx = (lane & 3)        + (wvx << 2);   // 0..15
    int ly = ((lane >> 2) & 3) + (wvy << 2);   // 0..7
    int lz = lane >> 4;                        // 0..3

    int W0 = blockIdx.x * 16;
    int H0 = blockIdx.y * 8;
    int zt = blockIdx.z;            // 0 .. (Dv/4)*Bv - 1
    int b  = zt / (Dv/4);           // uniform
    int Z0 = (zt % (Dv/4)) * 4;

    int w = W0 + lx, h = H0 + ly, z = Z0 + lz;

    const float* M = mats + b*12;   // uniform -> scalar loads
    float m00 = M[0], m01 = M[1],  m02 = M[2],  m03 = M[3];
    float m10 = M[4], m11 = M[5],  m12 = M[6],  m13 = M[7];
    float m20 = M[8], m21 = M[9],  m22 = M[10], m23 = M[11];

    // ix = m00*(w+.5) + m01*(h+.5) + m02*(z+.5) + Cx
    float Cx = 96.0f*(m03 - m00 - m01 - m02) + 95.5f;
    float Cy = 96.0f*(m13 - m10 - m11 - m12) + 95.5f;
    float Cz = 96.0f*(m23 - m20 - m21 - m22) + 95.5f;

    float fw = w + 0.5f, fh = h + 0.5f, fzc = z + 0.5f;
    float ix = fmaf(m00, fw, fmaf(m01, fh, fmaf(m02, fzc, Cx)));
    float iy = fmaf(m10, fw, fmaf(m11, fh, fmaf(m12, fzc, Cy)));
    float iz = fmaf(m20, fw, fmaf(m21, fh, fmaf(m22, fzc, Cz)));

    float flx = floorf(ix), fly = floorf(iy), flz = floorf(iz);
    float wx = ix - flx, wy = iy - fly, wz = iz - flz;
    int x0 = (int)flx, y0 = (int)fly, z0 = (int)flz;

    const float* sb = src + (size_t)b * Nv;

    float acc = 0.0f;

    bool all_in = ((unsigned)x0 < (unsigned)(Wv-1)) &
                  ((unsigned)y0 < (unsigned)(Hv-1)) &
                  ((unsigned)z0 < (unsigned)(Dv-1));

    if (all_in) {
        const float* p = sb + ((z0*Hv + y0)*Wv + x0);
        const float* q = p + Hv*Wv;
        float2 v00 = ld2(p);
        float2 v01 = ld2(p + Wv);
        float2 v10 = ld2(q);
        float2 v11 = ld2(q + Wv);
        float c00 = fmaf(wx, v00.y - v00.x, v00.x);
        float c01 = fmaf(wx, v01.y - v01.x, v01.x);
        float c10 = fmaf(wx, v10.y - v10.x, v10.x);
        float c11 = fmaf(wx, v11.y - v11.x, v11.x);
        float c0  = fmaf(wy, c01 - c00, c00);
        float c1  = fmaf(wy, c11 - c10, c10);
        acc = fmaf(wz, c1 - c0, c0);
    } else {
        int x1 = x0 + 1, y1 = y0 + 1, z1 = z0 + 1;
        bool all_out = (x1 < 0) | (x0 >= Wv) | (y1 < 0) | (y0 >= Hv) | (z1 < 0) | (z0 >= Dv);
        if (!all_out) {
            auto gather = [&](int zz, int yy, int xx) -> float {
                bool valid = ((unsigned)xx < (unsigned)Wv) &
                             ((unsigned)yy < (unsigned)Hv) &
                             ((unsigned)zz < (unsigned)Dv);
                int xi = min(max(xx, 0), Wv-1);
                int yi = min(max(yy, 0), Hv-1);
                int zi = min(max(zz, 0), Dv-1);
                float val = sb[(zi*Hv + yi)*Wv + xi];
                return valid ? val : 0.0f;
            };
            float owx = 1.0f - wx, owy = 1.0f - wy, owz = 1.0f - wz;
            acc  = gather(z0, y0, x0) * (owz*owy*owx);
            acc += gather(z0, y0, x1) * (owz*owy*wx);
            acc += gather(z0, y1, x0) * (owz*wy*owx);
            acc += gather(z0, y1, x1) * (owz*wy*wx);
            acc += gather(z1, y0, x0) * (wz*owy*owx);
            acc += gather(z1, y0, x1) * (wz*owy*wx);
            acc += gather(z1, y1, x0) * (wz*wy*owx);
            acc += gather(z1, y1, x1) * (wz*wy*wx);
        }
    }

    // LDS transpose: park acc at logical addr s = lx + 16*ly + 128*lz,
    // XOR-swizzled by lz so the cube-wave's write hits 32 distinct banks.
    int s = lx + (ly << 4) + (lz << 7);
    tileO[s ^ (lz << 2)] = acc;
    __syncthreads();

    // linear read-out: logical addr = t (z=t>>7), same swizzle (wave-uniform
    // XOR on read since (t>>7) is constant within a wave) -> conflict-free.
    float v = tileO[t ^ (((t >> 7) & 3) << 2)];

    int w2 = W0 + (t & 15);
    int h2 = H0 + ((t >> 4) & 7);
    int z2 = Z0 + (t >> 7);
    __builtin_nontemporal_store(v, &out[((size_t)(b*Dv + z2)*Hv + h2)*Wv + w2]);
}

extern "C" void kernel_launch(void* const* d_in, const int* in_sizes, int n_in,
                              void* d_out, int out_size, void* d_ws, size_t ws_size,
                              hipStream_t stream) {
    const float* src       = (const float*)d_in[0];
    const float* affine    = (const float*)d_in[1];
    const float* scale     = (const float*)d_in[2];
    const float* translate = (const float*)d_in[3];
    const float* shear     = (const float*)d_in[4];

    float* out  = (float*)d_out;
    float* mats = out + NOUT;   // mat (24 floats) then inv_mat (24 floats)

    compose_mats_kernel<<<1, 64, 0, stream>>>(affine, scale, translate, shear, mats);

    dim3 grid(Wv/16, Hv/8, (Dv/4)*Bv);
    warp_kernel<<<grid, 512, 0, stream>>>(src, mats, out);
}